// Round 1
// baseline (2792.673 us; speedup 1.0000x reference)
//
#include <hip/hip_runtime.h>

// LightGCN propagation: 3 layers of SpMM (scatter-add formulation) + running sum.
// N=250000 nodes, D=64, E=1.25M edges. All fp32.

#define U_NODES 100000
#define I_NODES 150000
#define N_NODES 250000
#define DIM 64
#define E_EDGES 1250000
#define LAYERS 3   // layer_num is a device scalar but fixed at 3 by setup_inputs();
                   // graph capture requires identical work per call, so hardcoded.

// ---- init: cur = acc = concat(user, item), vectorized float4 -----------------
__global__ void lgcn_init(const float* __restrict__ user,
                          const float* __restrict__ item,
                          float* __restrict__ cur,
                          float* __restrict__ acc) {
    long i = (long)blockIdx.x * blockDim.x + threadIdx.x;   // over N*D/4 float4s
    const long total = (long)N_NODES * (DIM / 4);
    if (i >= total) return;
    const long ucount = (long)U_NODES * (DIM / 4);
    float4 v = (i < ucount) ? ((const float4*)user)[i]
                            : ((const float4*)item)[i - ucount];
    ((float4*)cur)[i] = v;
    ((float4*)acc)[i] = v;
}

// ---- scatter SpMM: 16 lanes per edge, one float4 per lane --------------------
// next[row[e]] += (adj[e]*mask[e]) * cur[col[e]]
__global__ void lgcn_scatter(const int*   __restrict__ row,
                             const int*   __restrict__ col,
                             const float* __restrict__ adj,
                             const float* __restrict__ mask,
                             const float* __restrict__ cur,
                             float*       __restrict__ nxt) {
    long t = (long)blockIdx.x * blockDim.x + threadIdx.x;
    if (t >= (long)E_EDGES * 16) return;
    int e    = (int)(t >> 4);
    int part = (int)(t & 15);
    float v = adj[e] * mask[e];        // mask is exactly 0.0 or 1.0
    if (v == 0.0f) return;             // ~20% of edges dropped; uniform across the 16-lane group
    int c = col[e];
    int r = row[e];
    float4 x = ((const float4*)(cur + (long)c * DIM))[part];
    float* dst = nxt + (long)r * DIM + part * 4;
    atomicAdd(dst + 0, v * x.x);
    atomicAdd(dst + 1, v * x.y);
    atomicAdd(dst + 2, v * x.z);
    atomicAdd(dst + 3, v * x.w);
}

// ---- acc update: acc = (acc + nxt) * scale  (scale=1, last layer 0.25) -------
__global__ void lgcn_accum(const float* __restrict__ nxt,
                           float* __restrict__ acc,
                           float scale) {
    long i = (long)blockIdx.x * blockDim.x + threadIdx.x;
    const long total = (long)N_NODES * (DIM / 4);
    if (i >= total) return;
    float4 a = ((const float4*)acc)[i];
    float4 n = ((const float4*)nxt)[i];
    a.x = (a.x + n.x) * scale;
    a.y = (a.y + n.y) * scale;
    a.z = (a.z + n.z) * scale;
    a.w = (a.w + n.w) * scale;
    ((float4*)acc)[i] = a;
}

extern "C" void kernel_launch(void* const* d_in, const int* in_sizes, int n_in,
                              void* d_out, int out_size, void* d_ws, size_t ws_size,
                              hipStream_t stream) {
    const int*   row  = (const int*)d_in[0];
    const int*   col  = (const int*)d_in[1];
    const float* adj  = (const float*)d_in[2];
    const float* mask = (const float*)d_in[3];
    const float* user = (const float*)d_in[4];
    const float* item = (const float*)d_in[5];
    // d_in[6] = layer_num (device scalar, ==3; see LAYERS note above)

    float* acc = (float*)d_out;                        // N*DIM fp32
    const size_t node_bytes = (size_t)N_NODES * DIM * sizeof(float);  // 64 MB
    float* bufA = (float*)d_ws;
    float* bufB = (float*)((char*)d_ws + node_bytes);

    const int BLK = 256;
    const long node_vec4 = (long)N_NODES * (DIM / 4);          // 4,000,000
    const int  grid_node = (int)((node_vec4 + BLK - 1) / BLK); // 15625
    const long scat_thr  = (long)E_EDGES * 16;                 // 20,000,000
    const int  grid_scat = (int)((scat_thr + BLK - 1) / BLK);  // 78125

    lgcn_init<<<grid_node, BLK, 0, stream>>>(user, item, bufA, acc);

    float* cur = bufA;
    float* nxt = bufB;
    for (int l = 0; l < LAYERS; ++l) {
        hipMemsetAsync(nxt, 0, node_bytes, stream);
        lgcn_scatter<<<grid_scat, BLK, 0, stream>>>(row, col, adj, mask, cur, nxt);
        lgcn_accum<<<grid_node, BLK, 0, stream>>>(nxt, acc, (l == LAYERS - 1) ? 0.25f : 1.0f);
        float* tmp = cur; cur = nxt; nxt = tmp;
    }
}

// Round 2
// 428.061 us; speedup vs baseline: 6.5240x; 6.5240x over previous
//
#include <hip/hip_runtime.h>

// LightGCN propagation, pull-based CSR SpMM (no float atomics).
// N=250000 nodes, D=64 (=16 float4), E=1.25M edges, 3 layers. All fp32.
//
// Per call: build CSR of kept edges (mask!=0) via count/scan/fill, then
// 3 pull layers: out[r] = sum_e v[e]*cur[col[e]], acc += out, last layer *0.25.

#define U_NODES 100000
#define N_NODES 250000
#define DIM 64
#define DIM4 16            // DIM/4 float4 per row
#define E_EDGES 1250000
#define SCAN_TILE 1024     // elements per block in scan1 (256 thr x 4)

// ---- init: cur = concat(user, item) -----------------------------------------
__global__ void lgcn_init(const float* __restrict__ user,
                          const float* __restrict__ item,
                          float* __restrict__ cur) {
    long i = (long)blockIdx.x * blockDim.x + threadIdx.x;   // over N*DIM/4
    const long total = (long)N_NODES * DIM4;
    if (i >= total) return;
    const long ucount = (long)U_NODES * DIM4;
    float4 v = (i < ucount) ? ((const float4*)user)[i]
                            : ((const float4*)item)[i - ucount];
    ((float4*)cur)[i] = v;
}

// ---- CSR build step 1: per-row degree counts (kept edges only) ---------------
__global__ void lgcn_count(const int* __restrict__ row,
                           const float* __restrict__ mask,
                           int* __restrict__ counts) {
    int e = blockIdx.x * blockDim.x + threadIdx.x;
    if (e >= E_EDGES) return;
    if (mask[e] != 0.0f) atomicAdd(&counts[row[e]], 1);
}

// ---- CSR build step 2a: block-local exclusive scan + block totals ------------
__global__ void lgcn_scan1(const int* __restrict__ counts,
                           int* __restrict__ row_ptr,
                           int* __restrict__ partials) {
    __shared__ int lds[256];
    int t = threadIdx.x;
    int base = blockIdx.x * SCAN_TILE + t * 4;
    int4 c = make_int4(0, 0, 0, 0);
    if (base + 3 < N_NODES) {
        c = *(const int4*)(counts + base);
    } else {
        if (base + 0 < N_NODES) c.x = counts[base + 0];
        if (base + 1 < N_NODES) c.y = counts[base + 1];
        if (base + 2 < N_NODES) c.z = counts[base + 2];
        if (base + 3 < N_NODES) c.w = counts[base + 3];
    }
    int s = c.x + c.y + c.z + c.w;
    lds[t] = s;
    __syncthreads();
    for (int off = 1; off < 256; off <<= 1) {
        int v = (t >= off) ? lds[t - off] : 0;
        __syncthreads();
        if (t >= off) lds[t] += v;
        __syncthreads();
    }
    int incl = lds[t];
    int p = incl - s;   // exclusive prefix for this thread's 4 elements
    if (base + 0 < N_NODES) row_ptr[base + 0] = p; p += c.x;
    if (base + 1 < N_NODES) row_ptr[base + 1] = p; p += c.y;
    if (base + 2 < N_NODES) row_ptr[base + 2] = p; p += c.z;
    if (base + 3 < N_NODES) row_ptr[base + 3] = p;
    if (t == 255) partials[blockIdx.x] = incl;
}

// ---- CSR build step 2b: scan the block totals (single block, nblk<=256) ------
__global__ void lgcn_scan2(int* __restrict__ partials,
                           int* __restrict__ row_ptr_end,  // &row_ptr[N]
                           int nblk) {
    __shared__ int lds[256];
    int t = threadIdx.x;
    int v = (t < nblk) ? partials[t] : 0;
    lds[t] = v;
    __syncthreads();
    for (int off = 1; off < 256; off <<= 1) {
        int w = (t >= off) ? lds[t - off] : 0;
        __syncthreads();
        if (t >= off) lds[t] += w;
        __syncthreads();
    }
    int incl = lds[t];
    if (t < nblk) partials[t] = incl - v;       // exclusive
    if (t == 255) *row_ptr_end = lds[255];      // total kept edges
}

// ---- CSR build step 2c: add block offsets, init fill cursors -----------------
__global__ void lgcn_scan3(int* __restrict__ row_ptr,
                           int* __restrict__ cursor,
                           const int* __restrict__ partials) {
    int i = blockIdx.x * blockDim.x + threadIdx.x;
    if (i >= N_NODES) return;
    int v = row_ptr[i] + partials[i / SCAN_TILE];
    row_ptr[i] = v;
    cursor[i] = v;
}

// ---- CSR build step 3: scatter edges into CSR slots --------------------------
__global__ void lgcn_fill(const int* __restrict__ row,
                          const int* __restrict__ col,
                          const float* __restrict__ adj,
                          const float* __restrict__ mask,
                          int* __restrict__ cursor,
                          int2* __restrict__ csr) {   // {col, bitcast(val)}
    int e = blockIdx.x * blockDim.x + threadIdx.x;
    if (e >= E_EDGES) return;
    float m = mask[e];
    if (m == 0.0f) return;
    float v = adj[e] * m;
    int pos = atomicAdd(&cursor[row[e]], 1);
    csr[pos] = make_int2(col[e], __float_as_int(v));
}

// ---- pull SpMM layer: 16 lanes per row, one float4 slice per lane ------------
// nxt[r] = sum_e v*cur[col]; acc_new = (FIRST ? cur[r] : acc[r]) + nxt[r];
// LAST: acc_new *= 0.25, skip writing nxt.
template <bool FIRST, bool LAST>
__global__ void lgcn_pull(const int*    __restrict__ row_ptr,
                          const int2*   __restrict__ csr,
                          const float4* __restrict__ cur,
                          float4*       __restrict__ nxt,
                          float4*       __restrict__ acc) {
    int tid = blockIdx.x * blockDim.x + threadIdx.x;
    int r = tid >> 4;
    int part = tid & 15;
    if (r >= N_NODES) return;
    int start = row_ptr[r];
    int end   = row_ptr[r + 1];
    float4 s = make_float4(0.f, 0.f, 0.f, 0.f);
    for (int e = start; e < end; ++e) {
        int2 cv = csr[e];                       // lane-uniform within the 16-group
        float v = __int_as_float(cv.y);
        float4 x = cur[(long)cv.x * DIM4 + part];
        s.x += v * x.x;
        s.y += v * x.y;
        s.z += v * x.z;
        s.w += v * x.w;
    }
    long oi = (long)r * DIM4 + part;
    float4 a = FIRST ? cur[oi] : acc[oi];
    a.x += s.x; a.y += s.y; a.z += s.z; a.w += s.w;
    if (LAST) {
        a.x *= 0.25f; a.y *= 0.25f; a.z *= 0.25f; a.w *= 0.25f;
    } else {
        nxt[oi] = s;
    }
    acc[oi] = a;
}

extern "C" void kernel_launch(void* const* d_in, const int* in_sizes, int n_in,
                              void* d_out, int out_size, void* d_ws, size_t ws_size,
                              hipStream_t stream) {
    const int*   row  = (const int*)d_in[0];
    const int*   col  = (const int*)d_in[1];
    const float* adj  = (const float*)d_in[2];
    const float* mask = (const float*)d_in[3];
    const float* user = (const float*)d_in[4];
    const float* item = (const float*)d_in[5];
    // d_in[6] = layer_num (==3, hardcoded; graph capture needs identical work)

    float* acc = (float*)d_out;

    // workspace layout (all 16B-aligned)
    const size_t node_bytes = (size_t)N_NODES * DIM * sizeof(float);     // 64 MB
    char* ws = (char*)d_ws;
    float* bufA    = (float*)(ws);                                       // 64 MB
    float* bufB    = (float*)(ws + node_bytes);                          // 64 MB
    int*   row_ptr = (int*)(ws + 2 * node_bytes);                        // (N+1) ints
    size_t rp_bytes = ((size_t)(N_NODES + 1) * sizeof(int) + 15) & ~15ul;
    int*   cursor  = (int*)((char*)row_ptr + rp_bytes);                  // N ints (counts, then cursors)
    size_t cu_bytes = ((size_t)N_NODES * sizeof(int) + 15) & ~15ul;
    int*   partials = (int*)((char*)cursor + cu_bytes);                  // <=256 ints
    int2*  csr     = (int2*)((char*)partials + 256 * sizeof(int));       // E int2 = 10 MB

    const int BLK = 256;
    const long node_vec4 = (long)N_NODES * DIM4;                 // 4,000,000
    const int  grid_node = (int)((node_vec4 + BLK - 1) / BLK);   // 15625
    const int  grid_edge = (E_EDGES + BLK - 1) / BLK;            // 4883
    const int  nblk_scan = (N_NODES + SCAN_TILE - 1) / SCAN_TILE; // 245
    const int  grid_rows = (N_NODES + BLK - 1) / BLK;            // 977

    // init embeds
    lgcn_init<<<grid_node, BLK, 0, stream>>>(user, item, bufA);

    // CSR build
    hipMemsetAsync(cursor, 0, (size_t)N_NODES * sizeof(int), stream);    // counts
    lgcn_count<<<grid_edge, BLK, 0, stream>>>(row, mask, cursor);
    lgcn_scan1<<<nblk_scan, BLK, 0, stream>>>(cursor, row_ptr, partials);
    lgcn_scan2<<<1, BLK, 0, stream>>>(partials, row_ptr + N_NODES, nblk_scan);
    lgcn_scan3<<<grid_rows, BLK, 0, stream>>>(row_ptr, cursor, partials);
    lgcn_fill<<<grid_edge, BLK, 0, stream>>>(row, col, adj, mask, cursor, csr);

    // 3 pull layers (acc fused; last layer scales by 1/4 and skips nxt write)
    lgcn_pull<true,  false><<<grid_node, BLK, 0, stream>>>(row_ptr, csr, (const float4*)bufA, (float4*)bufB, (float4*)acc);
    lgcn_pull<false, false><<<grid_node, BLK, 0, stream>>>(row_ptr, csr, (const float4*)bufB, (float4*)bufA, (float4*)acc);
    lgcn_pull<false, true ><<<grid_node, BLK, 0, stream>>>(row_ptr, csr, (const float4*)bufA, (float4*)bufB, (float4*)acc);
}

// Round 3
// 381.423 us; speedup vs baseline: 7.3217x; 1.1223x over previous
//
#include <hip/hip_runtime.h>

// LightGCN propagation, pull-based CSR SpMM, no float atomics, no int atomics
// in fill (epos recorded during count). N=250000, D=64, E=1.25M, 3 layers, fp32.

#define U_NODES 100000
#define N_NODES 250000
#define DIM4 16            // 64 floats = 16 float4 per row
#define E_EDGES 1250000
#define SCAN_TILE 1024     // scan1: 256 threads x 4 elems

// ---- step 1: per-row kept-degree counts + per-edge rank within row -----------
__global__ void lgcn_count(const int* __restrict__ row,
                           const float* __restrict__ mask,
                           int* __restrict__ counts,   // zeroed before
                           int* __restrict__ epos) {
    int e = blockIdx.x * blockDim.x + threadIdx.x;
    if (e >= E_EDGES) return;
    if (mask[e] != 0.0f) epos[e] = atomicAdd(&counts[row[e]], 1);
}

// ---- step 2a: per-block exclusive scan of counts; block totals ---------------
// rp_local[i] = exclusive prefix of counts within block; last block also writes
// rp_local[N] = its local inclusive total (so final_rp(N) works).
__global__ void lgcn_scan1(const int* __restrict__ counts,
                           int* __restrict__ rp_local,
                           int* __restrict__ partials) {
    __shared__ int lds[256];
    int t = threadIdx.x;
    int base = blockIdx.x * SCAN_TILE + t * 4;
    int4 c = make_int4(0, 0, 0, 0);
    if (base + 3 < N_NODES) {
        c = *(const int4*)(counts + base);
    } else {
        if (base + 0 < N_NODES) c.x = counts[base + 0];
        if (base + 1 < N_NODES) c.y = counts[base + 1];
        if (base + 2 < N_NODES) c.z = counts[base + 2];
        if (base + 3 < N_NODES) c.w = counts[base + 3];
    }
    int s = c.x + c.y + c.z + c.w;
    lds[t] = s;
    __syncthreads();
    for (int off = 1; off < 256; off <<= 1) {
        int v = (t >= off) ? lds[t - off] : 0;
        __syncthreads();
        if (t >= off) lds[t] += v;
        __syncthreads();
    }
    int incl = lds[t];
    int p = incl - s;
    if (base + 0 < N_NODES) rp_local[base + 0] = p; p += c.x;
    if (base + 1 < N_NODES) rp_local[base + 1] = p; p += c.y;
    if (base + 2 < N_NODES) rp_local[base + 2] = p; p += c.z;
    if (base + 3 < N_NODES) rp_local[base + 3] = p;
    if (t == 255) {
        partials[blockIdx.x] = lds[255];
        if ((int)blockIdx.x == (int)gridDim.x - 1) rp_local[N_NODES] = lds[255];
    }
}

// ---- step 2b: exclusive scan of block totals in place (nblk<=256) ------------
__global__ void lgcn_scan2(int* __restrict__ partials, int nblk) {
    __shared__ int lds[256];
    int t = threadIdx.x;
    int v = (t < nblk) ? partials[t] : 0;
    lds[t] = v;
    __syncthreads();
    for (int off = 1; off < 256; off <<= 1) {
        int w = (t >= off) ? lds[t - off] : 0;
        __syncthreads();
        if (t >= off) lds[t] += w;
        __syncthreads();
    }
    if (t < nblk) partials[t] = lds[t] - v;   // exclusive
}

// final row_ptr value reconstructed on the fly:
__device__ __forceinline__ int final_rp(const int* rp_local, const int* blk_off, int i) {
    return rp_local[i] + blk_off[i >> 10];    // SCAN_TILE == 1024
}

// ---- step 3: place edges into CSR slots (no atomics) -------------------------
__global__ void lgcn_fill(const int* __restrict__ row,
                          const int* __restrict__ col,
                          const float* __restrict__ adj,
                          const float* __restrict__ mask,
                          const int* __restrict__ rp_local,
                          const int* __restrict__ blk_off,
                          const int* __restrict__ epos,
                          int2* __restrict__ csr) {   // {col, bitcast(val)}
    int e = blockIdx.x * blockDim.x + threadIdx.x;
    if (e >= E_EDGES) return;
    float m = mask[e];
    if (m == 0.0f) return;
    int r = row[e];
    int pos = final_rp(rp_local, blk_off, r) + epos[e];
    csr[pos] = make_int2(col[e], __float_as_int(adj[e] * m));
}

// ---- embed read for layer 1 (virtual concat of user/item) --------------------
__device__ __forceinline__ float4 emb_ui(const float4* __restrict__ u,
                                         const float4* __restrict__ it,
                                         int node, int part) {
    long idx = (long)node * DIM4 + part;
    const long uc = (long)U_NODES * DIM4;
    return (idx < uc) ? u[idx] : it[idx - uc];
}

// ---- pull SpMM layer: 16 lanes per row, one float4 slice per lane ------------
// s = sum_e v*emb(col); acc_new = (FIRST ? emb(r) : acc[r]) + s
// LAST: acc_new *= 0.25 and skip writing nxt.
template <bool FIRST, bool LAST>
__global__ void lgcn_pull(const int*    __restrict__ rp_local,
                          const int*    __restrict__ blk_off,
                          const int2*   __restrict__ csr,
                          const float4* __restrict__ user4,
                          const float4* __restrict__ item4,
                          const float4* __restrict__ cur,
                          float4*       __restrict__ nxt,
                          float4*       __restrict__ acc) {
    int tid = blockIdx.x * blockDim.x + threadIdx.x;
    int r = tid >> 4;
    int part = tid & 15;
    if (r >= N_NODES) return;
    int start = final_rp(rp_local, blk_off, r);
    int end   = final_rp(rp_local, blk_off, r + 1);
    float4 s = make_float4(0.f, 0.f, 0.f, 0.f);
    int e = start;
    // unroll x2: two independent csr->gather chains in flight
    for (; e + 2 <= end; e += 2) {
        int2 c0 = csr[e];
        int2 c1 = csr[e + 1];
        float4 x0 = FIRST ? emb_ui(user4, item4, c0.x, part)
                          : cur[(long)c0.x * DIM4 + part];
        float4 x1 = FIRST ? emb_ui(user4, item4, c1.x, part)
                          : cur[(long)c1.x * DIM4 + part];
        float v0 = __int_as_float(c0.y);
        float v1 = __int_as_float(c1.y);
        s.x += v0 * x0.x + v1 * x1.x;
        s.y += v0 * x0.y + v1 * x1.y;
        s.z += v0 * x0.z + v1 * x1.z;
        s.w += v0 * x0.w + v1 * x1.w;
    }
    if (e < end) {
        int2 c0 = csr[e];
        float4 x0 = FIRST ? emb_ui(user4, item4, c0.x, part)
                          : cur[(long)c0.x * DIM4 + part];
        float v0 = __int_as_float(c0.y);
        s.x += v0 * x0.x;
        s.y += v0 * x0.y;
        s.z += v0 * x0.z;
        s.w += v0 * x0.w;
    }
    long oi = (long)r * DIM4 + part;
    float4 a = FIRST ? emb_ui(user4, item4, r, part) : acc[oi];
    a.x += s.x; a.y += s.y; a.z += s.z; a.w += s.w;
    if (LAST) {
        a.x *= 0.25f; a.y *= 0.25f; a.z *= 0.25f; a.w *= 0.25f;
    } else {
        nxt[oi] = s;
    }
    acc[oi] = a;
}

extern "C" void kernel_launch(void* const* d_in, const int* in_sizes, int n_in,
                              void* d_out, int out_size, void* d_ws, size_t ws_size,
                              hipStream_t stream) {
    const int*   row  = (const int*)d_in[0];
    const int*   col  = (const int*)d_in[1];
    const float* adj  = (const float*)d_in[2];
    const float* mask = (const float*)d_in[3];
    const float4* user4 = (const float4*)d_in[4];
    const float4* item4 = (const float4*)d_in[5];
    // d_in[6] = layer_num (==3, hardcoded; graph capture needs identical work)

    float4* acc = (float4*)d_out;

    // workspace layout (16B aligned)
    const size_t node_bytes = (size_t)N_NODES * DIM4 * sizeof(float4);   // 64 MB
    char* ws = (char*)d_ws;
    float4* bufA    = (float4*)(ws);                                     // 64 MB
    float4* bufB    = (float4*)(ws + node_bytes);                        // 64 MB
    int*   rp_local = (int*)(ws + 2 * node_bytes);                       // N+1 ints
    size_t rp_bytes = (((size_t)(N_NODES + 1) * 4) + 15) & ~15ul;
    int*   counts   = (int*)((char*)rp_local + rp_bytes);                // N ints
    size_t ct_bytes = (((size_t)N_NODES * 4) + 15) & ~15ul;
    int*   blk_off  = (int*)((char*)counts + ct_bytes);                  // 256 ints
    int*   epos     = (int*)((char*)blk_off + 256 * 4);                  // E ints
    size_t ep_bytes = (((size_t)E_EDGES * 4) + 15) & ~15ul;
    int2*  csr      = (int2*)((char*)epos + ep_bytes);                   // E int2

    const int BLK = 256;
    const long node_vec4 = (long)N_NODES * DIM4;                  // 4,000,000
    const int  grid_node = (int)((node_vec4 + BLK - 1) / BLK);    // 15625
    const int  grid_edge = (E_EDGES + BLK - 1) / BLK;             // 4883
    const int  nblk_scan = (N_NODES + SCAN_TILE - 1) / SCAN_TILE; // 245

    hipMemsetAsync(counts, 0, (size_t)N_NODES * sizeof(int), stream);
    lgcn_count<<<grid_edge, BLK, 0, stream>>>(row, mask, counts, epos);
    lgcn_scan1<<<nblk_scan, BLK, 0, stream>>>(counts, rp_local, blk_off /*unused arg pos*/);
    lgcn_scan2<<<1, BLK, 0, stream>>>(blk_off, nblk_scan);
    lgcn_fill<<<grid_edge, BLK, 0, stream>>>(row, col, adj, mask, rp_local, blk_off, epos, csr);

    // layer 1: reads user/item directly (no init pass); writes bufB + acc
    lgcn_pull<true,  false><<<grid_node, BLK, 0, stream>>>(rp_local, blk_off, csr, user4, item4, bufA /*unused*/, bufB, acc);
    // layer 2: bufB -> bufA, acc +=
    lgcn_pull<false, false><<<grid_node, BLK, 0, stream>>>(rp_local, blk_off, csr, user4, item4, bufB, bufA, acc);
    // layer 3: bufA -> (none), acc = (acc+s)*0.25
    lgcn_pull<false, true ><<<grid_node, BLK, 0, stream>>>(rp_local, blk_off, csr, user4, item4, bufA, bufB /*unused*/, acc);
}